// Round 7
// baseline (454.172 us; speedup 1.0000x reference)
//
#include <hip/hip_runtime.h>
#include <math.h>

// HDCFactMemory, single-pass fused scan with decoupled lookback.
//   out = x + r_gate[b,t] * K[d] * sign(S[b,t,d]) * sign(x[b,t,d])
//   K[d] = sign(role_write[d])*sign(role_read[d])   (factored out, exact)
//   S[b,t,d] = sum_{t'<=t} sign(x[b,t',d]) * w_gate[b,t']
// All sign-determining arithmetic in f64 (np-f64 reference; R2-R6 validated).
//
// Block = one T-chunk of TC=8 rows, staged once into 128KB LDS and kept for
// the whole lifetime: gates (f64 row dots), chunk aggregate, lookback,
// rescan + NT-store. x touches HBM exactly once; out written once (NT).
// Ticketed chunk assignment (atomic counter) makes lookback deadlock-free:
// a chunk's predecessors always hold earlier tickets -> started earlier.

#define T_LEN 4096
#define D_LEN 4096
#define TC 8               // rows per chunk (slab = 8 x 16KB = 128KB LDS)
#define NC (T_LEN / TC)    // 512 chunks per batch
#define D4 (D_LEN / 4)     // 1024 float4 per row
#define NTHR 1024

typedef float nfloat4 __attribute__((ext_vector_type(4)));

__device__ __forceinline__ float fsgn(float v) {
    return (v > 0.f) ? 1.f : ((v < 0.f) ? -1.f : 0.f);
}
__device__ __forceinline__ double dsgn(double v) {
    return (v > 0.) ? 1. : ((v < 0.) ? -1. : 0.);
}

__global__ __launch_bounds__(NTHR) void init_kernel(
    unsigned* __restrict__ flags, unsigned* __restrict__ counter, int nch)
{
    const int i = blockIdx.x * NTHR + threadIdx.x;
    if (i < nch) flags[i] = 0u;
    if (i == nch) *counter = 0u;
}

__global__ __launch_bounds__(NTHR, 1) void fused_kernel(
    const float* __restrict__ x,
    const float* __restrict__ role_w, const float* __restrict__ role_r,
    const float* __restrict__ wg_w, const float* __restrict__ wg_b,
    const float* __restrict__ rg_w, const float* __restrict__ rg_b,
    unsigned* __restrict__ counter, unsigned* __restrict__ flags,
    double* __restrict__ aggr, double* __restrict__ incl,
    float* __restrict__ out)
{
    __shared__ float xs[TC * D_LEN];            // 128 KB slab
    __shared__ double gredw[TC][2], gredr[TC][2];
    __shared__ double wsm[TC];
    __shared__ float rsm[TC];
    __shared__ unsigned s_ch, s_st;

    const int tid = threadIdx.x;

    // ---- ticket: chunk assignment in strictly increasing order ----
    if (tid == 0) s_ch = atomicAdd(counter, 1u);
    __syncthreads();
    const unsigned ch = s_ch;
    const int b = ch / NC, c = ch % NC;

    // ---- stage slab (x read ONCE from HBM) ----
    const float4* xg = (const float4*)(x + ((size_t)b * T_LEN + (size_t)c * TC) * D_LEN);
    float4* xl = (float4*)xs;
    #pragma unroll
    for (int j = 0; j < (TC * D4) / NTHR; ++j)   // 8 iterations
        xl[tid + j * NTHR] = xg[tid + j * NTHR];
    __syncthreads();

    // ---- gates: 128 threads (2 waves) per row, f64 dot from LDS ----
    {
        const int r = tid >> 7, k = tid & 127;
        const float4* row = (const float4*)(xs + r * D_LEN);
        const float4* w4 = (const float4*)wg_w;
        const float4* g4 = (const float4*)rg_w;
        double dw = 0., dg = 0.;
        #pragma unroll
        for (int j = 0; j < 8; ++j) {
            float4 v = row[k + j * 128];
            float4 a = w4[k + j * 128];
            float4 g = g4[k + j * 128];
            dw += (double)v.x * a.x + (double)v.y * a.y
                + (double)v.z * a.z + (double)v.w * a.w;
            dg += (double)v.x * g.x + (double)v.y * g.y
                + (double)v.z * g.z + (double)v.w * g.w;
        }
        for (int off = 32; off > 0; off >>= 1) {
            dw += __shfl_down(dw, off);
            dg += __shfl_down(dg, off);
        }
        if ((tid & 63) == 0) {
            gredw[r][(tid >> 6) & 1] = dw;
            gredr[r][(tid >> 6) & 1] = dg;
        }
    }
    __syncthreads();
    if (tid < TC) {
        double zw = gredw[tid][0] + gredw[tid][1] + (double)wg_b[0];
        double zr = gredr[tid][0] + gredr[tid][1] + (double)rg_b[0];
        wsm[tid] = 1. / (1. + exp(-zw));
        rsm[tid] = (float)(1. / (1. + exp(-zr)));
    }
    __syncthreads();

    // ---- chunk aggregate: thread owns 4 consecutive columns ----
    double ag0 = 0., ag1 = 0., ag2 = 0., ag3 = 0.;
    #pragma unroll
    for (int t = 0; t < TC; ++t) {
        float4 v = ((const float4*)xs)[t * D4 + tid];
        double w = wsm[t];
        ag0 += (double)fsgn(v.x) * w;
        ag1 += (double)fsgn(v.y) * w;
        ag2 += (double)fsgn(v.z) * w;
        ag3 += (double)fsgn(v.w) * w;
    }
    {   // publish aggregate (flag = 1)
        double* arec = aggr + (size_t)ch * D_LEN + tid * 4;
        arec[0] = ag0; arec[1] = ag1; arec[2] = ag2; arec[3] = ag3;
    }
    __syncthreads();
    if (tid == 0) {
        __threadfence();
        __hip_atomic_store(&flags[ch], 1u, __ATOMIC_RELEASE, __HIP_MEMORY_SCOPE_AGENT);
    }

    // ---- decoupled lookback (within batch b) ----
    double ex0 = 0., ex1 = 0., ex2 = 0., ex3 = 0.;
    for (int p = c - 1; p >= 0; --p) {
        if (tid == 0) {
            unsigned st;
            while ((st = __hip_atomic_load(&flags[b * NC + p], __ATOMIC_ACQUIRE,
                                           __HIP_MEMORY_SCOPE_AGENT)) == 0u)
                __builtin_amdgcn_s_sleep(2);
            s_st = st;
        }
        __syncthreads();
        const unsigned st = s_st;
        const double* rec = (st == 2u ? incl : aggr)
                          + (size_t)(b * NC + p) * D_LEN + tid * 4;
        ex0 += rec[0]; ex1 += rec[1]; ex2 += rec[2]; ex3 += rec[3];
        __syncthreads();           // protect s_st before next iteration
        if (st == 2u) break;       // uniform across block
    }

    {   // publish inclusive (flag = 2)
        double* irec = incl + (size_t)ch * D_LEN + tid * 4;
        irec[0] = ex0 + ag0; irec[1] = ex1 + ag1;
        irec[2] = ex2 + ag2; irec[3] = ex3 + ag3;
    }
    __syncthreads();
    if (tid == 0) {
        __threadfence();
        __hip_atomic_store(&flags[ch], 2u, __ATOMIC_RELEASE, __HIP_MEMORY_SCOPE_AGENT);
    }

    // ---- rescan slab from LDS, write out (NT stores) ----
    float4 rw = ((const float4*)role_w)[tid];
    float4 rr = ((const float4*)role_r)[tid];
    const float kx = fsgn(rw.x) * fsgn(rr.x);
    const float ky = fsgn(rw.y) * fsgn(rr.y);
    const float kz = fsgn(rw.z) * fsgn(rr.z);
    const float kw = fsgn(rw.w) * fsgn(rr.w);

    nfloat4* o4 = (nfloat4*)(out + ((size_t)b * T_LEN + (size_t)c * TC) * D_LEN);
    #pragma unroll
    for (int t = 0; t < TC; ++t) {
        float4 v = ((const float4*)xs)[t * D4 + tid];
        double w = wsm[t];
        float rf = rsm[t];
        float sx = fsgn(v.x), sy = fsgn(v.y), sz = fsgn(v.z), sw2 = fsgn(v.w);
        ex0 += (double)sx * w; ex1 += (double)sy * w;
        ex2 += (double)sz * w; ex3 += (double)sw2 * w;
        nfloat4 o;
        o.x = v.x + rf * kx * (float)dsgn(ex0) * sx;
        o.y = v.y + rf * ky * (float)dsgn(ex1) * sy;
        o.z = v.z + rf * kz * (float)dsgn(ex2) * sz;
        o.w = v.w + rf * kw * (float)dsgn(ex3) * sw2;
        __builtin_nontemporal_store(o, &o4[t * D4 + tid]);
    }
}

extern "C" void kernel_launch(void* const* d_in, const int* in_sizes, int n_in,
                              void* d_out, int out_size, void* d_ws, size_t ws_size,
                              hipStream_t stream) {
    const float* x      = (const float*)d_in[0];
    const float* role_w = (const float*)d_in[1];
    const float* role_r = (const float*)d_in[2];
    const float* wg_w   = (const float*)d_in[3];
    const float* wg_b   = (const float*)d_in[4];
    const float* rg_w   = (const float*)d_in[5];
    const float* rg_b   = (const float*)d_in[6];
    float* out = (float*)d_out;

    const int B = in_sizes[0] / (T_LEN * D_LEN);   // = 2
    const int NCH = B * NC;                        // 1024 chunks

    // ws (512 MiB available): aggr[NCH*D] f64, incl[NCH*D] f64, flags, counter
    double* aggr = (double*)d_ws;
    double* incl = aggr + (size_t)NCH * D_LEN;
    unsigned* flags = (unsigned*)(incl + (size_t)NCH * D_LEN);
    unsigned* counter = flags + NCH;

    init_kernel<<<(NCH + 1 + NTHR - 1) / NTHR, NTHR, 0, stream>>>(flags, counter, NCH);
    fused_kernel<<<NCH, NTHR, 0, stream>>>(
        x, role_w, role_r, wg_w, wg_b, rg_w, rg_b,
        counter, flags, aggr, incl, out);
}